// Round 12
// baseline (736.528 us; speedup 1.0000x reference)
//
#include <hip/hip_runtime.h>
#include <hip/hip_bf16.h>
#include <cmath>

#define NSEQ 480
#define SEQN 128
#define CDIM 256
#define NH 8
#define HD 32
#define TOPM 20

typedef float f32x4 __attribute__((ext_vector_type(4)));
typedef short bf16x8 __attribute__((ext_vector_type(8)));

__device__ __forceinline__ unsigned short bf16_rn(float x) {
    unsigned int u = __float_as_uint(x);
    unsigned int r = (u + 0x7FFFu + ((u >> 16) & 1u)) >> 16;
    return (unsigned short)r;
}
__device__ __forceinline__ float bf16f(unsigned short h) {
    return __uint_as_float(((unsigned int)h) << 16);
}
__device__ __forceinline__ unsigned pk_bf16(float a, float b) {
    union { __hip_bfloat162 h; unsigned u; } cv;
    cv.h = __float22bfloat162_rn(make_float2(a, b));
    return cv.u;
}
__device__ __forceinline__ void unpack_bf16x8(uint4 u, float* o) {
    o[0] = bf16f((unsigned short)(u.x & 0xffffu)); o[1] = bf16f((unsigned short)(u.x >> 16));
    o[2] = bf16f((unsigned short)(u.y & 0xffffu)); o[3] = bf16f((unsigned short)(u.y >> 16));
    o[4] = bf16f((unsigned short)(u.z & 0xffffu)); o[5] = bf16f((unsigned short)(u.z >> 16));
    o[6] = bf16f((unsigned short)(u.w & 0xffffu)); o[7] = bf16f((unsigned short)(u.w >> 16));
}
// one ulp above x (x finite); used as exclusive upper bisection bound
__device__ __forceinline__ float ulp_above(float x) {
    x = x + 0.0f;  // -0 -> +0
    unsigned u = __float_as_uint(x);
    u = (x >= 0.f) ? u + 1u : u - 1u;
    return __uint_as_float(u);
}

// ---------------------------------------------------------------------------
// K1: transpose (B, C, N) -> (B, N, C), add pos_embed, emit split-bf16 planes.
__global__ __launch_bounds__(256) void prep_kernel(const float* __restrict__ RW,
                                                   const float* __restrict__ POS,
                                                   unsigned short* __restrict__ XH,
                                                   unsigned short* __restrict__ XL) {
    int b = blockIdx.x, n0 = blockIdx.y * 32, c0 = blockIdx.z * 32;
    __shared__ float tile[32][33];
    int tx = threadIdx.x & 31, ty = threadIdx.x >> 5;
#pragma unroll
    for (int jj = 0; jj < 4; ++jj) {
        int c = c0 + ty + 8 * jj;
        tile[ty + 8 * jj][tx] = RW[((size_t)b * CDIM + c) * SEQN + n0 + tx];
    }
    __syncthreads();
    const int cp = threadIdx.x & 15;
    const int nr = threadIdx.x >> 4;
#pragma unroll
    for (int pass = 0; pass < 2; ++pass) {
        int n = n0 + nr + 16 * pass;
        int c = c0 + cp * 2;
        const float* prow = POS + (size_t)n * CDIM + c;
        float v0 = tile[cp * 2 + 0][nr + 16 * pass] + prow[0];
        float v1 = tile[cp * 2 + 1][nr + 16 * pass] + prow[1];
        unsigned short h0 = bf16_rn(v0), h1 = bf16_rn(v1);
        unsigned short l0 = bf16_rn(v0 - bf16f(h0)), l1 = bf16_rn(v1 - bf16f(h1));
        size_t widx = ((size_t)b * SEQN * CDIM + (size_t)n * CDIM + c) >> 1;
        reinterpret_cast<unsigned*>(XH)[widx] = (unsigned)h0 | ((unsigned)h1 << 16);
        reinterpret_cast<unsigned*>(XL)[widx] = (unsigned)l0 | ((unsigned)l1 << 16);
    }
}

// ---------------------------------------------------------------------------
// K1b: ALL weight splits (both layers) in one launch.
__global__ __launch_bounds__(256) void wsplit_all_kernel(
    const float* __restrict__ Wq0, const float* __restrict__ Wp0,
    const float* __restrict__ Wq1, const float* __restrict__ Wp1,
    unsigned short* __restrict__ WBUF) {
    int k0 = blockIdx.x * 32;
    int yy = blockIdx.y;
    int li = yy >> 5;
    int ys = yy & 31;
    const size_t QN = (size_t)768 * 256, PN = (size_t)256 * 256;
    const size_t LSTRIDE = 2 * QN + 2 * PN;
    unsigned short* base = WBUF + li * LSTRIDE;
    const float* W;
    unsigned short *WH, *WL;
    int ncols, j0;
    if (ys < 24) {
        W = li ? Wq1 : Wq0; WH = base; WL = base + QN; ncols = 768; j0 = ys * 32;
    } else {
        W = li ? Wp1 : Wp0; WH = base + 2 * QN; WL = base + 2 * QN + PN; ncols = 256; j0 = (ys - 24) * 32;
    }
    __shared__ float tile[32][33];
    int tx = threadIdx.x & 31, ty = threadIdx.x >> 5;
#pragma unroll
    for (int jj = 0; jj < 4; ++jj)
        tile[ty + 8 * jj][tx] = W[(size_t)(k0 + ty + 8 * jj) * ncols + j0 + tx];
    __syncthreads();
#pragma unroll
    for (int jj = 0; jj < 4; ++jj) {
        float v = tile[tx][ty + 8 * jj];
        unsigned short hi = bf16_rn(v);
        unsigned short lo = bf16_rn(v - bf16f(hi));
        size_t idx = (size_t)(j0 + ty + 8 * jj) * 256 + k0 + tx;
        WH[idx] = hi;
        WL[idx] = lo;
    }
}

// ---------------------------------------------------------------------------
// K2: fused qkv + exact top-20 attention (round-5 structure).
// Selection: interpolation-guided exact bracket search (alternating with
// midpoint for worst-case); tree reductions for max/min/sum; raw v_exp_f32.
__global__ __launch_bounds__(256, 4) void attn_kernel(
    const unsigned short* __restrict__ XHi, const unsigned short* __restrict__ XLo,
    unsigned short* __restrict__ OH,
    const unsigned short* __restrict__ WtHi, const unsigned short* __restrict__ WtLo,
    const float* __restrict__ BIAS) {
    const int bid = blockIdx.x;
    const int h = (bid >> 3) & 7;
    const int b = ((bid >> 6) << 3) | (bid & 7);
    const float scale2 = 0.25503486f;  // (1/sqrt(32)) * log2(e)

    __shared__ unsigned short qh[SEQN * HD], ql[SEQN * HD];
    __shared__ unsigned short kh[SEQN * HD], kl[SEQN * HD];
    __shared__ unsigned short vh[HD * SEQN];

    const int tid = threadIdx.x;
    const int w = tid >> 6;
    const int l = tid & 63;
    const int l15 = l & 15;
    const int sct = l >> 4;
    const size_t xbase = (size_t)b * SEQN * CDIM;

    // ================= Phase 1: QKV via MFMA =================
    f32x4 acc[2][6];  // ni 0,1=q  2,3=k  4,5=v
#pragma unroll
    for (int mi = 0; mi < 2; ++mi)
#pragma unroll
        for (int ni = 0; ni < 6; ++ni) acc[mi][ni] = (f32x4){0.f, 0.f, 0.f, 0.f};

#pragma unroll 2
    for (int ks = 0; ks < 8; ++ks) {
        const int kb = ks * 32;
        bf16x8 ahi[2], alo[2];
#pragma unroll
        for (int mi = 0; mi < 2; ++mi) {
            int row = w * 32 + mi * 16 + l15;
            size_t off = xbase + row * CDIM + kb + sct * 8;
            ahi[mi] = *reinterpret_cast<const bf16x8*>(XHi + off);
            alo[mi] = *reinterpret_cast<const bf16x8*>(XLo + off);
        }
#pragma unroll
        for (int ni = 0; ni < 6; ++ni) {
            int j = ((ni >> 1) << 8) + h * HD + ((ni & 1) << 4) + l15;
            const int woff = j * 256 + kb + sct * 8;
            bf16x8 bh = *reinterpret_cast<const bf16x8*>(WtHi + woff);
            if (ni < 4) {
                bf16x8 bl = *reinterpret_cast<const bf16x8*>(WtLo + woff);
#pragma unroll
                for (int mi = 0; mi < 2; ++mi) {
                    acc[mi][ni] = __builtin_amdgcn_mfma_f32_16x16x32_bf16(ahi[mi], bh, acc[mi][ni], 0, 0, 0);
                    acc[mi][ni] = __builtin_amdgcn_mfma_f32_16x16x32_bf16(ahi[mi], bl, acc[mi][ni], 0, 0, 0);
                    acc[mi][ni] = __builtin_amdgcn_mfma_f32_16x16x32_bf16(alo[mi], bh, acc[mi][ni], 0, 0, 0);
                }
            } else {
#pragma unroll
                for (int mi = 0; mi < 2; ++mi)
                    acc[mi][ni] = __builtin_amdgcn_mfma_f32_16x16x32_bf16(ahi[mi], bh, acc[mi][ni], 0, 0, 0);
            }
        }
    }
#pragma unroll
    for (int ni = 0; ni < 6; ++ni) {
        const int sel = ni >> 1;
        const int dcol = ((ni & 1) << 4) + l15;
        const float bias = BIAS[(sel << 8) + h * HD + dcol];
#pragma unroll
        for (int mi = 0; mi < 2; ++mi) {
            const int tb = w * 32 + mi * 16 + sct * 4;
            if (sel == 2) {
                float v0 = acc[mi][ni][0] + bias, v1 = acc[mi][ni][1] + bias;
                float v2 = acc[mi][ni][2] + bias, v3 = acc[mi][ni][3] + bias;
                unsigned pA = pk_bf16(v0, v1), pB = pk_bf16(v2, v3);
                int c0i = tb ^ ((dcol & 7) << 3);
                *reinterpret_cast<uint2*>(&vh[dcol * SEQN + c0i]) = make_uint2(pA, pB);
            } else {
                unsigned short* ph = sel ? kh : qh;
                unsigned short* pl = sel ? kl : ql;
#pragma unroll
                for (int r = 0; r < 4; ++r) {
                    float v = acc[mi][ni][r] + bias;
                    if (sel == 0) v *= scale2;
                    unsigned short hi = bf16_rn(v);
                    int token = tb + r;
                    int idx = token * HD + (dcol ^ (((token >> 1) & 3) << 3));
                    ph[idx] = hi;
                    pl[idx] = bf16_rn(v - bf16f(hi));
                }
            }
        }
    }
    __syncthreads();

    // ================= Phase 2: S^T = K·Q^T, in-register softmax ============
    f32x4 sacc[8][2];
#pragma unroll
    for (int mi = 0; mi < 8; ++mi)
#pragma unroll
        for (int ni = 0; ni < 2; ++ni) sacc[mi][ni] = (f32x4){0.f, 0.f, 0.f, 0.f};

    bf16x8 qfh[2], qfl[2];
#pragma unroll
    for (int ni = 0; ni < 2; ++ni) {
        int qrow = w * 32 + (ni << 4) + l15;
        int off = qrow * HD + ((sct * 8) ^ (((qrow >> 1) & 3) << 3));
        qfh[ni] = *reinterpret_cast<const bf16x8*>(qh + off);
        qfl[ni] = *reinterpret_cast<const bf16x8*>(ql + off);
    }
    __builtin_amdgcn_s_setprio(1);
#pragma unroll
    for (int mi = 0; mi < 8; ++mi) {
        int krow = (mi << 4) + l15;
        int off = krow * HD + ((sct * 8) ^ (((krow >> 1) & 3) << 3));
        bf16x8 kfh = *reinterpret_cast<const bf16x8*>(kh + off);
        bf16x8 kfl = *reinterpret_cast<const bf16x8*>(kl + off);
#pragma unroll
        for (int ni = 0; ni < 2; ++ni) {
            sacc[mi][ni] = __builtin_amdgcn_mfma_f32_16x16x32_bf16(kfh, qfh[ni], sacc[mi][ni], 0, 0, 0);
            sacc[mi][ni] = __builtin_amdgcn_mfma_f32_16x16x32_bf16(kfh, qfl[ni], sacc[mi][ni], 0, 0, 0);
            sacc[mi][ni] = __builtin_amdgcn_mfma_f32_16x16x32_bf16(kfl, qfh[ni], sacc[mi][ni], 0, 0, 0);
        }
    }
    __builtin_amdgcn_s_setprio(0);

    // row max/min: tree reduction (depth ~5 instead of 31)
    float pmx0[8], pmn0[8], pmx1[8], pmn1[8];
#pragma unroll
    for (int mi = 0; mi < 8; ++mi) {
        pmx0[mi] = fmaxf(fmaxf(sacc[mi][0][0], sacc[mi][0][1]), fmaxf(sacc[mi][0][2], sacc[mi][0][3]));
        pmn0[mi] = fminf(fminf(sacc[mi][0][0], sacc[mi][0][1]), fminf(sacc[mi][0][2], sacc[mi][0][3]));
        pmx1[mi] = fmaxf(fmaxf(sacc[mi][1][0], sacc[mi][1][1]), fmaxf(sacc[mi][1][2], sacc[mi][1][3]));
        pmn1[mi] = fminf(fminf(sacc[mi][1][0], sacc[mi][1][1]), fminf(sacc[mi][1][2], sacc[mi][1][3]));
    }
    float mx0 = fmaxf(fmaxf(fmaxf(pmx0[0], pmx0[1]), fmaxf(pmx0[2], pmx0[3])),
                      fmaxf(fmaxf(pmx0[4], pmx0[5]), fmaxf(pmx0[6], pmx0[7])));
    float mn0 = fminf(fminf(fminf(pmn0[0], pmn0[1]), fminf(pmn0[2], pmn0[3])),
                      fminf(fminf(pmn0[4], pmn0[5]), fminf(pmn0[6], pmn0[7])));
    float mx1 = fmaxf(fmaxf(fmaxf(pmx1[0], pmx1[1]), fmaxf(pmx1[2], pmx1[3])),
                      fmaxf(fmaxf(pmx1[4], pmx1[5]), fmaxf(pmx1[6], pmx1[7])));
    float mn1 = fminf(fminf(fminf(pmn1[0], pmn1[1]), fminf(pmn1[2], pmn1[3])),
                      fminf(fminf(pmn1[4], pmn1[5]), fminf(pmn1[6], pmn1[7])));
    mx0 = fmaxf(mx0, __shfl_xor(mx0, 16));
    mx0 = fmaxf(mx0, __shfl_xor(mx0, 32));
    mx1 = fmaxf(mx1, __shfl_xor(mx1, 16));
    mx1 = fmaxf(mx1, __shfl_xor(mx1, 32));
    mn0 = fminf(mn0, __shfl_xor(mn0, 16));
    mn0 = fminf(mn0, __shfl_xor(mn0, 32));
    mn1 = fminf(mn1, __shfl_xor(mn1, 16));
    mn1 = fminf(mn1, __shfl_xor(mn1, 32));

    // exact top-20 threshold: interpolation-guided bracket search on
    // [mn, ulp_above(mx)).  Invariants: count(lo) >= TOPM > count(hi).
    // Early exit at c==TOPM (mask == top-20 exactly); terminal 1-ulp
    // bracket -> thr = lo = kth (tie semantics match reference s >= kth).
    // Odd iterations use plain midpoint (worst-case bisection bound).
    float p0f, p1f;
    {
        float lo0 = mn0, hi0 = ulp_above(mx0), lo1 = mn1, hi1 = ulp_above(mx1);
        float clo0 = 128.f, chi0 = 0.f, clo1 = 128.f, chi1 = 0.f;
        float th0 = mx0, th1 = mx1;
        int dn0 = 0, dn1 = 0;
#pragma unroll 1
        for (int it = 0; it < 64; ++it) {
            if (__all(dn0 & dn1)) break;
            float mid0, mid1;
            if (it & 1) {
                mid0 = 0.5f * (lo0 + hi0);
                mid1 = 0.5f * (lo1 + hi1);
            } else {
                mid0 = lo0 + (hi0 - lo0) * ((clo0 - (float)TOPM) / (clo0 - chi0));
                mid1 = lo1 + (hi1 - lo1) * ((clo1 - (float)TOPM) / (clo1 - chi1));
            }
            if (!(mid0 > lo0 && mid0 < hi0)) mid0 = 0.5f * (lo0 + hi0);
            if (!(mid1 > lo1 && mid1 < hi1)) mid1 = 0.5f * (lo1 + hi1);
            int c0 = 0, c1 = 0;
#pragma unroll
            for (int mi = 0; mi < 8; ++mi)
#pragma unroll
                for (int r = 0; r < 4; ++r) {
                    c0 += (sacc[mi][0][r] >= mid0) ? 1 : 0;
                    c1 += (sacc[mi][1][r] >= mid1) ? 1 : 0;
                }
            int mpk = c0 | (c1 << 8);
            mpk += __shfl_xor(mpk, 16);
            mpk += __shfl_xor(mpk, 32);
            c0 = mpk & 255;
            c1 = mpk >> 8;
            if (!dn0) {
                if (c0 == TOPM) { th0 = mid0; dn0 = 1; }
                else if (!(mid0 > lo0 && mid0 < hi0)) { th0 = lo0; dn0 = 1; }
                else if (c0 > TOPM) { lo0 = mid0; clo0 = (float)c0; }
                else { hi0 = mid0; chi0 = (float)c0; }
            }
            if (!dn1) {
                if (c1 == TOPM) { th1 = mid1; dn1 = 1; }
                else if (!(mid1 > lo1 && mid1 < hi1)) { th1 = lo1; dn1 = 1; }
                else if (c1 > TOPM) { lo1 = mid1; clo1 = (float)c1; }
                else { hi1 = mid1; chi1 = (float)c1; }
            }
        }
        p0f = th0; p1f = th1;
    }

    // masked exp2 (scores pre-scaled by log2e); per-mi partials + tree sum
    float ps0[8], ps1[8];
#pragma unroll
    for (int mi = 0; mi < 8; ++mi) {
        float e00 = (sacc[mi][0][0] >= p0f) ? __builtin_amdgcn_exp2f(sacc[mi][0][0] - mx0) : 0.f;
        float e01 = (sacc[mi][0][1] >= p0f) ? __builtin_amdgcn_exp2f(sacc[mi][0][1] - mx0) : 0.f;
        float e02 = (sacc[mi][0][2] >= p0f) ? __builtin_amdgcn_exp2f(sacc[mi][0][2] - mx0) : 0.f;
        float e03 = (sacc[mi][0][3] >= p0f) ? __builtin_amdgcn_exp2f(sacc[mi][0][3] - mx0) : 0.f;
        float e10 = (sacc[mi][1][0] >= p1f) ? __builtin_amdgcn_exp2f(sacc[mi][1][0] - mx1) : 0.f;
        float e11 = (sacc[mi][1][1] >= p1f) ? __builtin_amdgcn_exp2f(sacc[mi][1][1] - mx1) : 0.f;
        float e12 = (sacc[mi][1][2] >= p1f) ? __builtin_amdgcn_exp2f(sacc[mi][1][2] - mx1) : 0.f;
        float e13 = (sacc[mi][1][3] >= p1f) ? __builtin_amdgcn_exp2f(sacc[mi][1][3] - mx1) : 0.f;
        sacc[mi][0][0] = e00; sacc[mi][0][1] = e01; sacc[mi][0][2] = e02; sacc[mi][0][3] = e03;
        sacc[mi][1][0] = e10; sacc[mi][1][1] = e11; sacc[mi][1][2] = e12; sacc[mi][1][3] = e13;
        ps0[mi] = (e00 + e01) + (e02 + e03);
        ps1[mi] = (e10 + e11) + (e12 + e13);
    }
    float s0 = ((ps0[0] + ps0[1]) + (ps0[2] + ps0[3])) + ((ps0[4] + ps0[5]) + (ps0[6] + ps0[7]));
    float s1 = ((ps1[0] + ps1[1]) + (ps1[2] + ps1[3])) + ((ps1[4] + ps1[5]) + (ps1[6] + ps1[7]));
    s0 += __shfl_xor(s0, 16);
    s0 += __shfl_xor(s0, 32);
    s1 += __shfl_xor(s1, 16);
    s1 += __shfl_xor(s1, 32);
    float i0 = 1.f / s0, i1 = 1.f / s1;

    // ================= Phase 3: O = P·V via MFMA (per-k weight pack) ========
    f32x4 oacc[2][2];
#pragma unroll
    for (int mi = 0; mi < 2; ++mi)
#pragma unroll
        for (int ni = 0; ni < 2; ++ni) oacc[mi][ni] = (f32x4){0.f, 0.f, 0.f, 0.f};

#pragma unroll
    for (int k = 0; k < 4; ++k) {
        unsigned w16k[2][2][2];  // [mi-offset][ni][pair]
#pragma unroll
        for (int m2 = 0; m2 < 2; ++m2)
#pragma unroll
            for (int ni = 0; ni < 2; ++ni)
#pragma unroll
                for (int p = 0; p < 2; ++p)
                    w16k[m2][ni][p] = pk_bf16(sacc[2 * k + m2][ni][2 * p], sacc[2 * k + m2][ni][2 * p + 1]);
        bf16x8 bvh[2];
#pragma unroll
        for (int nio = 0; nio < 2; ++nio) {
            int drow = (nio << 4) + l15;
            int off = drow * SEQN + ((k * 32 + sct * 8) ^ ((drow & 7) << 3));
            bvh[nio] = *reinterpret_cast<const bf16x8*>(vh + off);
        }
#pragma unroll
        for (int mio = 0; mio < 2; ++mio) {
            union { unsigned u[4]; bf16x8 v8; } aw;
#pragma unroll
            for (int j = 0; j < 4; ++j) {
                int src = l15 + ((sct & 1) << 5) + ((j >> 1) << 4);
                unsigned a0 = (unsigned)__shfl((int)w16k[0][mio][j & 1], src);
                unsigned a1 = (unsigned)__shfl((int)w16k[1][mio][j & 1], src);
                aw.u[j] = (sct >= 2) ? a1 : a0;
            }
            __builtin_amdgcn_s_setprio(1);
#pragma unroll
            for (int nio = 0; nio < 2; ++nio)
                oacc[mio][nio] = __builtin_amdgcn_mfma_f32_16x16x32_bf16(aw.v8, bvh[nio], oacc[mio][nio], 0, 0, 0);
            __builtin_amdgcn_s_setprio(0);
        }
    }
    float invO[2][4];
#pragma unroll
    for (int mio = 0; mio < 2; ++mio)
#pragma unroll
        for (int r = 0; r < 4; ++r)
            invO[mio][r] = __shfl(mio ? i1 : i0, sct * 4 + r);
#pragma unroll
    for (int mio = 0; mio < 2; ++mio)
#pragma unroll
        for (int nio = 0; nio < 2; ++nio)
#pragma unroll
            for (int r = 0; r < 4; ++r) {
                int token = w * 32 + mio * 16 + sct * 4 + r;
                int d = (nio << 4) + l15;
                size_t idx = ((size_t)b * SEQN + token) * CDIM + h * HD + d;
                OH[idx] = bf16_rn(oacc[mio][nio][r] * invO[mio][r]);
            }
}

// ---------------------------------------------------------------------------
// K3: MFMA proj GEMM (A = single-bf16 O, B split -> 2-term) + bias + residual
// + LayerNorm, 32 tokens per block.  grid (480, 4), block 256.
__global__ __launch_bounds__(256, 4) void projln_kernel(
    const unsigned short* __restrict__ OHp,
    unsigned short* __restrict__ XH, unsigned short* __restrict__ XL,
    const unsigned short* __restrict__ W2H, const unsigned short* __restrict__ W2L,
    const float* __restrict__ PB, const float* __restrict__ G,
    const float* __restrict__ BB) {
    const int b = blockIdx.x;
    const int t0 = blockIdx.y * 32;
    __shared__ float vals[32 * 289];
    __shared__ float part[8][32][2];

    const int tid = threadIdx.x;
    const int w = tid >> 6;
    const int l = tid & 63;
    const int l15 = l & 15;
    const int sct = l >> 4;

    f32x4 acc[2][4];
#pragma unroll
    for (int mi = 0; mi < 2; ++mi)
#pragma unroll
        for (int ni = 0; ni < 4; ++ni) acc[mi][ni] = (f32x4){0.f, 0.f, 0.f, 0.f};

    const size_t obase = ((size_t)b * SEQN + t0) * CDIM;
#pragma unroll 2
    for (int ks = 0; ks < 8; ++ks) {
        const int kb = ks * 32;
        bf16x8 ahi[2];
#pragma unroll
        for (int mi = 0; mi < 2; ++mi) {
            size_t off = obase + (size_t)(mi * 16 + l15) * CDIM + kb + sct * 8;
            ahi[mi] = *reinterpret_cast<const bf16x8*>(OHp + off);
        }
#pragma unroll
        for (int ni = 0; ni < 4; ++ni) {
            int j = w * 64 + ni * 16 + l15;
            int woff = j * 256 + kb + sct * 8;
            bf16x8 bh = *reinterpret_cast<const bf16x8*>(W2H + woff);
            bf16x8 bl = *reinterpret_cast<const bf16x8*>(W2L + woff);
#pragma unroll
            for (int mi = 0; mi < 2; ++mi) {
                acc[mi][ni] = __builtin_amdgcn_mfma_f32_16x16x32_bf16(ahi[mi], bh, acc[mi][ni], 0, 0, 0);
                acc[mi][ni] = __builtin_amdgcn_mfma_f32_16x16x32_bf16(ahi[mi], bl, acc[mi][ni], 0, 0, 0);
            }
        }
    }
#pragma unroll
    for (int ni = 0; ni < 4; ++ni) {
        int j = w * 64 + ni * 16 + l15;
        float bias = PB[j];
#pragma unroll
        for (int mi = 0; mi < 2; ++mi)
#pragma unroll
            for (int r = 0; r < 4; ++r) {
                int tok = mi * 16 + sct * 4 + r;
                vals[tok * 289 + j] = acc[mi][ni][r] + bias;
            }
    }
    __syncthreads();

    const int row = tid & 31;
    const int cc = tid >> 5;
    const size_t rbase = ((size_t)b * SEQN + t0 + row) * CDIM + cc * 32;
    float v[32];
    {
        float ps = 0.f, pq = 0.f;
#pragma unroll
        for (int q = 0; q < 4; ++q) {
            uint4 hb = *reinterpret_cast<const uint4*>(XH + rbase + q * 8);
            uint4 lb = *reinterpret_cast<const uint4*>(XL + rbase + q * 8);
            float rh[8], rl[8];
            unpack_bf16x8(hb, rh);
            unpack_bf16x8(lb, rl);
#pragma unroll
            for (int jj = 0; jj < 8; ++jj) {
                int col = cc * 32 + q * 8 + jj;
                float val = vals[row * 289 + col] + rh[jj] + rl[jj];
                v[q * 8 + jj] = val;
                ps += val;
                pq = fmaf(val, val, pq);
            }
        }
        part[cc][row][0] = ps;
        part[cc][row][1] = pq;
    }
    __syncthreads();
    float s1 = 0.f, s2 = 0.f;
#pragma unroll
    for (int k = 0; k < 8; ++k) { s1 += part[k][row][0]; s2 += part[k][row][1]; }
    float m = s1 * (1.f / 256.f);
    float var = s2 * (1.f / 256.f) - m * m;
    float rstd = rsqrtf(var + 1e-5f);
#pragma unroll
    for (int q = 0; q < 4; ++q) {
        int col0 = cc * 32 + q * 8;
        float4 g0 = *reinterpret_cast<const float4*>(G + col0);
        float4 g1 = *reinterpret_cast<const float4*>(G + col0 + 4);
        float4 b0 = *reinterpret_cast<const float4*>(BB + col0);
        float4 b1 = *reinterpret_cast<const float4*>(BB + col0 + 4);
        float gg[8] = {g0.x, g0.y, g0.z, g0.w, g1.x, g1.y, g1.z, g1.w};
        float bb2[8] = {b0.x, b0.y, b0.z, b0.w, b1.x, b1.y, b1.z, b1.w};
        unsigned hw[4], lw[4];
#pragma unroll
        for (int p2 = 0; p2 < 4; ++p2) {
            float y0 = (v[q * 8 + p2 * 2] - m) * rstd * gg[p2 * 2] + bb2[p2 * 2];
            float y1 = (v[q * 8 + p2 * 2 + 1] - m) * rstd * gg[p2 * 2 + 1] + bb2[p2 * 2 + 1];
            unsigned short h0 = bf16_rn(y0), h1 = bf16_rn(y1);
            unsigned short lo0 = bf16_rn(y0 - bf16f(h0)), lo1 = bf16_rn(y1 - bf16f(h1));
            hw[p2] = (unsigned)h0 | ((unsigned)h1 << 16);
            lw[p2] = (unsigned)lo0 | ((unsigned)lo1 << 16);
        }
        *reinterpret_cast<uint4*>(XH + rbase + q * 8) = make_uint4(hw[0], hw[1], hw[2], hw[3]);
        *reinterpret_cast<uint4*>(XL + rbase + q * 8) = make_uint4(lw[0], lw[1], lw[2], lw[3]);
    }
}

// ---------------------------------------------------------------------------
// K4: mean over tokens + classifier head (reads planes). grid 480, block 256.
__global__ __launch_bounds__(256) void cls_kernel(const unsigned short* __restrict__ XH,
                                                  const unsigned short* __restrict__ XL,
                                                  const float* __restrict__ W1,
                                                  const float* __restrict__ B1,
                                                  const float* __restrict__ W2,
                                                  const float* __restrict__ B2,
                                                  float* __restrict__ OUT) {
    int b = blockIdx.x;
    __shared__ float xm[256];
    __shared__ float hred[128];
    int tid = threadIdx.x;
    float sm = 0.f;
    for (int n = 0; n < SEQN; ++n) {
        size_t idx = ((size_t)b * SEQN + n) * CDIM + tid;
        sm += bf16f(XH[idx]) + bf16f(XL[idx]);
    }
    xm[tid] = sm * (1.f / 128.f);
    __syncthreads();
    if (tid < 128) {
        float a = B1[tid];
        for (int k = 0; k < CDIM; ++k) a = fmaf(xm[k], W1[k * 128 + tid], a);
        a = fmaxf(a, 0.f);
        hred[tid] = a * W2[tid];
    }
    __syncthreads();
    for (int off = 64; off > 0; off >>= 1) {
        if (tid < off) hred[tid] += hred[tid + off];
        __syncthreads();
    }
    if (tid == 0) OUT[b] = hred[0] + B2[0];
}

// ---------------------------------------------------------------------------
extern "C" void kernel_launch(void* const* d_in, const int* in_sizes, int n_in,
                              void* d_out, int out_size, void* d_ws, size_t ws_size,
                              hipStream_t stream) {
    const float* RW  = (const float*)d_in[0];
    const float* POS = (const float*)d_in[1];
    const float* CW1 = (const float*)d_in[2];
    const float* CB1 = (const float*)d_in[3];
    const float* CW2 = (const float*)d_in[4];
    const float* CB2 = (const float*)d_in[5];

    const size_t NTOK = (size_t)NSEQ * SEQN * CDIM;  // 15.7M
    const size_t QN = (size_t)768 * 256, PN = (size_t)256 * 256;
    const size_t LSTRIDE = 2 * QN + 2 * PN;
    unsigned short* OH = (unsigned short*)d_ws;       // 31.5 MB
    unsigned short* XH = OH + NTOK;                   // 31.5 MB
    unsigned short* XL = XH + NTOK;                   // 31.5 MB
    unsigned short* WBUF = XL + NTOK;                 // 2 layers x 1.05 MB

    prep_kernel<<<dim3(NSEQ, 4, 8), 256, 0, stream>>>(RW, POS, XH, XL);
    wsplit_all_kernel<<<dim3(8, 64), 256, 0, stream>>>(
        (const float*)d_in[6], (const float*)d_in[8],
        (const float*)d_in[12], (const float*)d_in[14], WBUF);

    for (int li = 0; li < 2; ++li) {
        const float* qb = (const float*)d_in[7 + 6 * li];
        const float* pb = (const float*)d_in[9 + 6 * li];
        const float* lg = (const float*)d_in[10 + 6 * li];
        const float* lb = (const float*)d_in[11 + 6 * li];
        unsigned short* WtHi = WBUF + li * LSTRIDE;
        unsigned short* WtLo = WtHi + QN;
        unsigned short* W2H = WtHi + 2 * QN;
        unsigned short* W2L = W2H + PN;
        attn_kernel<<<NSEQ * NH, 256, 0, stream>>>(XH, XL, OH, WtHi, WtLo, qb);
        projln_kernel<<<dim3(NSEQ, 4), 256, 0, stream>>>(OH, XH, XL, W2H, W2L, pb, lg, lb);
    }

    cls_kernel<<<NSEQ, 256, 0, stream>>>(XH, XL, CW1, CB1, CW2, CB2, (float*)d_out);
}

// Round 13
// 725.320 us; speedup vs baseline: 1.0155x; 1.0155x over previous
//
#include <hip/hip_runtime.h>
#include <hip/hip_bf16.h>
#include <cmath>

#define NSEQ 480
#define SEQN 128
#define CDIM 256
#define NH 8
#define HD 32
#define TOPM 20

typedef float f32x4 __attribute__((ext_vector_type(4)));
typedef short bf16x8 __attribute__((ext_vector_type(8)));

__device__ __forceinline__ unsigned short bf16_rn(float x) {
    unsigned int u = __float_as_uint(x);
    unsigned int r = (u + 0x7FFFu + ((u >> 16) & 1u)) >> 16;
    return (unsigned short)r;
}
__device__ __forceinline__ float bf16f(unsigned short h) {
    return __uint_as_float(((unsigned int)h) << 16);
}
__device__ __forceinline__ unsigned pk_bf16(float a, float b) {
    union { __hip_bfloat162 h; unsigned u; } cv;
    cv.h = __float22bfloat162_rn(make_float2(a, b));
    return cv.u;
}
__device__ __forceinline__ void unpack_bf16x8(uint4 u, float* o) {
    o[0] = bf16f((unsigned short)(u.x & 0xffffu)); o[1] = bf16f((unsigned short)(u.x >> 16));
    o[2] = bf16f((unsigned short)(u.y & 0xffffu)); o[3] = bf16f((unsigned short)(u.y >> 16));
    o[4] = bf16f((unsigned short)(u.z & 0xffffu)); o[5] = bf16f((unsigned short)(u.z >> 16));
    o[6] = bf16f((unsigned short)(u.w & 0xffffu)); o[7] = bf16f((unsigned short)(u.w >> 16));
}
// one ulp above x (x finite); used as exclusive upper bisection bound
__device__ __forceinline__ float ulp_above(float x) {
    x = x + 0.0f;  // -0 -> +0
    unsigned u = __float_as_uint(x);
    u = (x >= 0.f) ? u + 1u : u - 1u;
    return __uint_as_float(u);
}

// ---------------------------------------------------------------------------
// K1: transpose (B, C, N) -> (B, N, C), add pos_embed, emit split-bf16 planes.
__global__ __launch_bounds__(256) void prep_kernel(const float* __restrict__ RW,
                                                   const float* __restrict__ POS,
                                                   unsigned short* __restrict__ XH,
                                                   unsigned short* __restrict__ XL) {
    int b = blockIdx.x, n0 = blockIdx.y * 32, c0 = blockIdx.z * 32;
    __shared__ float tile[32][33];
    int tx = threadIdx.x & 31, ty = threadIdx.x >> 5;
#pragma unroll
    for (int jj = 0; jj < 4; ++jj) {
        int c = c0 + ty + 8 * jj;
        tile[ty + 8 * jj][tx] = RW[((size_t)b * CDIM + c) * SEQN + n0 + tx];
    }
    __syncthreads();
    const int cp = threadIdx.x & 15;
    const int nr = threadIdx.x >> 4;
#pragma unroll
    for (int pass = 0; pass < 2; ++pass) {
        int n = n0 + nr + 16 * pass;
        int c = c0 + cp * 2;
        const float* prow = POS + (size_t)n * CDIM + c;
        float v0 = tile[cp * 2 + 0][nr + 16 * pass] + prow[0];
        float v1 = tile[cp * 2 + 1][nr + 16 * pass] + prow[1];
        unsigned short h0 = bf16_rn(v0), h1 = bf16_rn(v1);
        unsigned short l0 = bf16_rn(v0 - bf16f(h0)), l1 = bf16_rn(v1 - bf16f(h1));
        size_t widx = ((size_t)b * SEQN * CDIM + (size_t)n * CDIM + c) >> 1;
        reinterpret_cast<unsigned*>(XH)[widx] = (unsigned)h0 | ((unsigned)h1 << 16);
        reinterpret_cast<unsigned*>(XL)[widx] = (unsigned)l0 | ((unsigned)l1 << 16);
    }
}

// ---------------------------------------------------------------------------
// K1b: ALL weight splits (both layers) in one launch.
__global__ __launch_bounds__(256) void wsplit_all_kernel(
    const float* __restrict__ Wq0, const float* __restrict__ Wp0,
    const float* __restrict__ Wq1, const float* __restrict__ Wp1,
    unsigned short* __restrict__ WBUF) {
    int k0 = blockIdx.x * 32;
    int yy = blockIdx.y;
    int li = yy >> 5;
    int ys = yy & 31;
    const size_t QN = (size_t)768 * 256, PN = (size_t)256 * 256;
    const size_t LSTRIDE = 2 * QN + 2 * PN;
    unsigned short* base = WBUF + li * LSTRIDE;
    const float* W;
    unsigned short *WH, *WL;
    int ncols, j0;
    if (ys < 24) {
        W = li ? Wq1 : Wq0; WH = base; WL = base + QN; ncols = 768; j0 = ys * 32;
    } else {
        W = li ? Wp1 : Wp0; WH = base + 2 * QN; WL = base + 2 * QN + PN; ncols = 256; j0 = (ys - 24) * 32;
    }
    __shared__ float tile[32][33];
    int tx = threadIdx.x & 31, ty = threadIdx.x >> 5;
#pragma unroll
    for (int jj = 0; jj < 4; ++jj)
        tile[ty + 8 * jj][tx] = W[(size_t)(k0 + ty + 8 * jj) * ncols + j0 + tx];
    __syncthreads();
#pragma unroll
    for (int jj = 0; jj < 4; ++jj) {
        float v = tile[tx][ty + 8 * jj];
        unsigned short hi = bf16_rn(v);
        unsigned short lo = bf16_rn(v - bf16f(hi));
        size_t idx = (size_t)(j0 + ty + 8 * jj) * 256 + k0 + tx;
        WH[idx] = hi;
        WL[idx] = lo;
    }
}

// ---------------------------------------------------------------------------
// K2: fused qkv + exact top-20 attention (round-5 structure; best measured).
// Selection: FLOAT-domain bracketed bisection (value-scale convergence),
// exact w.r.t. computed scores incl. ties; softmax via exp2 with log2e
// folded into the q scale (order/mask/values unchanged).
__global__ __launch_bounds__(256, 4) void attn_kernel(
    const unsigned short* __restrict__ XHi, const unsigned short* __restrict__ XLo,
    unsigned short* __restrict__ OH,
    const unsigned short* __restrict__ WtHi, const unsigned short* __restrict__ WtLo,
    const float* __restrict__ BIAS) {
    const int bid = blockIdx.x;
    const int h = (bid >> 3) & 7;
    const int b = ((bid >> 6) << 3) | (bid & 7);
    const float scale2 = 0.25503486f;  // (1/sqrt(32)) * log2(e)

    __shared__ unsigned short qh[SEQN * HD], ql[SEQN * HD];
    __shared__ unsigned short kh[SEQN * HD], kl[SEQN * HD];
    __shared__ unsigned short vh[HD * SEQN];

    const int tid = threadIdx.x;
    const int w = tid >> 6;
    const int l = tid & 63;
    const int l15 = l & 15;
    const int sct = l >> 4;
    const size_t xbase = (size_t)b * SEQN * CDIM;

    // ================= Phase 1: QKV via MFMA =================
    f32x4 acc[2][6];  // ni 0,1=q  2,3=k  4,5=v
#pragma unroll
    for (int mi = 0; mi < 2; ++mi)
#pragma unroll
        for (int ni = 0; ni < 6; ++ni) acc[mi][ni] = (f32x4){0.f, 0.f, 0.f, 0.f};

#pragma unroll 2
    for (int ks = 0; ks < 8; ++ks) {
        const int kb = ks * 32;
        bf16x8 ahi[2], alo[2];
#pragma unroll
        for (int mi = 0; mi < 2; ++mi) {
            int row = w * 32 + mi * 16 + l15;
            size_t off = xbase + row * CDIM + kb + sct * 8;
            ahi[mi] = *reinterpret_cast<const bf16x8*>(XHi + off);
            alo[mi] = *reinterpret_cast<const bf16x8*>(XLo + off);
        }
#pragma unroll
        for (int ni = 0; ni < 6; ++ni) {
            int j = ((ni >> 1) << 8) + h * HD + ((ni & 1) << 4) + l15;
            const int woff = j * 256 + kb + sct * 8;
            bf16x8 bh = *reinterpret_cast<const bf16x8*>(WtHi + woff);
            if (ni < 4) {
                bf16x8 bl = *reinterpret_cast<const bf16x8*>(WtLo + woff);
#pragma unroll
                for (int mi = 0; mi < 2; ++mi) {
                    acc[mi][ni] = __builtin_amdgcn_mfma_f32_16x16x32_bf16(ahi[mi], bh, acc[mi][ni], 0, 0, 0);
                    acc[mi][ni] = __builtin_amdgcn_mfma_f32_16x16x32_bf16(ahi[mi], bl, acc[mi][ni], 0, 0, 0);
                    acc[mi][ni] = __builtin_amdgcn_mfma_f32_16x16x32_bf16(alo[mi], bh, acc[mi][ni], 0, 0, 0);
                }
            } else {
#pragma unroll
                for (int mi = 0; mi < 2; ++mi)
                    acc[mi][ni] = __builtin_amdgcn_mfma_f32_16x16x32_bf16(ahi[mi], bh, acc[mi][ni], 0, 0, 0);
            }
        }
    }
#pragma unroll
    for (int ni = 0; ni < 6; ++ni) {
        const int sel = ni >> 1;
        const int dcol = ((ni & 1) << 4) + l15;
        const float bias = BIAS[(sel << 8) + h * HD + dcol];
#pragma unroll
        for (int mi = 0; mi < 2; ++mi) {
            const int tb = w * 32 + mi * 16 + sct * 4;
            if (sel == 2) {
                float v0 = acc[mi][ni][0] + bias, v1 = acc[mi][ni][1] + bias;
                float v2 = acc[mi][ni][2] + bias, v3 = acc[mi][ni][3] + bias;
                unsigned pA = pk_bf16(v0, v1), pB = pk_bf16(v2, v3);
                int c0i = tb ^ ((dcol & 7) << 3);
                *reinterpret_cast<uint2*>(&vh[dcol * SEQN + c0i]) = make_uint2(pA, pB);
            } else {
                unsigned short* ph = sel ? kh : qh;
                unsigned short* pl = sel ? kl : ql;
#pragma unroll
                for (int r = 0; r < 4; ++r) {
                    float v = acc[mi][ni][r] + bias;
                    if (sel == 0) v *= scale2;
                    unsigned short hi = bf16_rn(v);
                    int token = tb + r;
                    int idx = token * HD + (dcol ^ (((token >> 1) & 3) << 3));
                    ph[idx] = hi;
                    pl[idx] = bf16_rn(v - bf16f(hi));
                }
            }
        }
    }
    __syncthreads();

    // ================= Phase 2: S^T = K·Q^T, in-register softmax ============
    f32x4 sacc[8][2];
#pragma unroll
    for (int mi = 0; mi < 8; ++mi)
#pragma unroll
        for (int ni = 0; ni < 2; ++ni) sacc[mi][ni] = (f32x4){0.f, 0.f, 0.f, 0.f};

    bf16x8 qfh[2], qfl[2];
#pragma unroll
    for (int ni = 0; ni < 2; ++ni) {
        int qrow = w * 32 + (ni << 4) + l15;
        int off = qrow * HD + ((sct * 8) ^ (((qrow >> 1) & 3) << 3));
        qfh[ni] = *reinterpret_cast<const bf16x8*>(qh + off);
        qfl[ni] = *reinterpret_cast<const bf16x8*>(ql + off);
    }
    __builtin_amdgcn_s_setprio(1);
#pragma unroll
    for (int mi = 0; mi < 8; ++mi) {
        int krow = (mi << 4) + l15;
        int off = krow * HD + ((sct * 8) ^ (((krow >> 1) & 3) << 3));
        bf16x8 kfh = *reinterpret_cast<const bf16x8*>(kh + off);
        bf16x8 kfl = *reinterpret_cast<const bf16x8*>(kl + off);
#pragma unroll
        for (int ni = 0; ni < 2; ++ni) {
            sacc[mi][ni] = __builtin_amdgcn_mfma_f32_16x16x32_bf16(kfh, qfh[ni], sacc[mi][ni], 0, 0, 0);
            sacc[mi][ni] = __builtin_amdgcn_mfma_f32_16x16x32_bf16(kfh, qfl[ni], sacc[mi][ni], 0, 0, 0);
            sacc[mi][ni] = __builtin_amdgcn_mfma_f32_16x16x32_bf16(kfl, qfh[ni], sacc[mi][ni], 0, 0, 0);
        }
    }
    __builtin_amdgcn_s_setprio(0);

    // row max and min (float domain, 4 lanes per row: xor 16, 32)
    float mx0 = sacc[0][0][0], mn0 = sacc[0][0][0];
    float mx1 = sacc[0][1][0], mn1 = sacc[0][1][0];
#pragma unroll
    for (int mi = 0; mi < 8; ++mi)
#pragma unroll
        for (int r = 0; r < 4; ++r) {
            float u0 = sacc[mi][0][r], u1 = sacc[mi][1][r];
            mx0 = fmaxf(mx0, u0); mn0 = fminf(mn0, u0);
            mx1 = fmaxf(mx1, u1); mn1 = fminf(mn1, u1);
        }
    mx0 = fmaxf(mx0, __shfl_xor(mx0, 16));
    mx0 = fmaxf(mx0, __shfl_xor(mx0, 32));
    mx1 = fmaxf(mx1, __shfl_xor(mx1, 16));
    mx1 = fmaxf(mx1, __shfl_xor(mx1, 32));
    mn0 = fminf(mn0, __shfl_xor(mn0, 16));
    mn0 = fminf(mn0, __shfl_xor(mn0, 32));
    mn1 = fminf(mn1, __shfl_xor(mn1, 16));
    mn1 = fminf(mn1, __shfl_xor(mn1, 32));

    // exact top-20 threshold per q-row: FLOAT bisection on [mn, ulp_above(mx)).
    // invariants: count(lo) >= TOPM, count(hi) < TOPM.  Early exit at c==TOPM
    // (mask == top-20 exactly); terminal 1-ulp bracket -> thr = kth (ties ok).
    float p0f, p1f;
    {
        float lo0 = mn0, hi0 = ulp_above(mx0), lo1 = mn1, hi1 = ulp_above(mx1);
        float th0 = mx0, th1 = mx1;
        int dn0 = 0, dn1 = 0;
#pragma unroll 1
        for (int it = 0; it < 48; ++it) {
            if (__all(dn0 & dn1)) break;
            float mid0 = 0.5f * (lo0 + hi0);
            float mid1 = 0.5f * (lo1 + hi1);
            int c0 = 0, c1 = 0;
#pragma unroll
            for (int mi = 0; mi < 8; ++mi)
#pragma unroll
                for (int r = 0; r < 4; ++r) {
                    c0 += (sacc[mi][0][r] >= mid0) ? 1 : 0;
                    c1 += (sacc[mi][1][r] >= mid1) ? 1 : 0;
                }
            int mpk = c0 | (c1 << 8);
            mpk += __shfl_xor(mpk, 16);
            mpk += __shfl_xor(mpk, 32);
            c0 = mpk & 255;
            c1 = mpk >> 8;
            if (!dn0) {
                if (c0 == TOPM) { th0 = mid0; dn0 = 1; }
                else if (mid0 <= lo0 || mid0 >= hi0) { th0 = lo0; dn0 = 1; }
                else if (c0 > TOPM) lo0 = mid0;
                else hi0 = mid0;
            }
            if (!dn1) {
                if (c1 == TOPM) { th1 = mid1; dn1 = 1; }
                else if (mid1 <= lo1 || mid1 >= hi1) { th1 = lo1; dn1 = 1; }
                else if (c1 > TOPM) lo1 = mid1;
                else hi1 = mid1;
            }
        }
        p0f = th0; p1f = th1;
    }

    // masked exp2 (scores are pre-scaled by log2e) + row sums
    float s0 = 0.f, s1 = 0.f;
#pragma unroll
    for (int mi = 0; mi < 8; ++mi)
#pragma unroll
        for (int r = 0; r < 4; ++r) {
            float v0 = sacc[mi][0][r], v1 = sacc[mi][1][r];
            float e0 = (v0 >= p0f) ? exp2f(v0 - mx0) : 0.f;
            float e1 = (v1 >= p1f) ? exp2f(v1 - mx1) : 0.f;
            sacc[mi][0][r] = e0;
            sacc[mi][1][r] = e1;
            s0 += e0;
            s1 += e1;
        }
    s0 += __shfl_xor(s0, 16);
    s0 += __shfl_xor(s0, 32);
    s1 += __shfl_xor(s1, 16);
    s1 += __shfl_xor(s1, 32);
    float i0 = 1.f / s0, i1 = 1.f / s1;

    // ================= Phase 3: O = P·V via MFMA (per-k weight pack) ========
    f32x4 oacc[2][2];
#pragma unroll
    for (int mi = 0; mi < 2; ++mi)
#pragma unroll
        for (int ni = 0; ni < 2; ++ni) oacc[mi][ni] = (f32x4){0.f, 0.f, 0.f, 0.f};

#pragma unroll
    for (int k = 0; k < 4; ++k) {
        unsigned w16k[2][2][2];  // [mi-offset][ni][pair]
#pragma unroll
        for (int m2 = 0; m2 < 2; ++m2)
#pragma unroll
            for (int ni = 0; ni < 2; ++ni)
#pragma unroll
                for (int p = 0; p < 2; ++p)
                    w16k[m2][ni][p] = pk_bf16(sacc[2 * k + m2][ni][2 * p], sacc[2 * k + m2][ni][2 * p + 1]);
        bf16x8 bvh[2];
#pragma unroll
        for (int nio = 0; nio < 2; ++nio) {
            int drow = (nio << 4) + l15;
            int off = drow * SEQN + ((k * 32 + sct * 8) ^ ((drow & 7) << 3));
            bvh[nio] = *reinterpret_cast<const bf16x8*>(vh + off);
        }
#pragma unroll
        for (int mio = 0; mio < 2; ++mio) {
            union { unsigned u[4]; bf16x8 v8; } aw;
#pragma unroll
            for (int j = 0; j < 4; ++j) {
                int src = l15 + ((sct & 1) << 5) + ((j >> 1) << 4);
                unsigned a0 = (unsigned)__shfl((int)w16k[0][mio][j & 1], src);
                unsigned a1 = (unsigned)__shfl((int)w16k[1][mio][j & 1], src);
                aw.u[j] = (sct >= 2) ? a1 : a0;
            }
            __builtin_amdgcn_s_setprio(1);
#pragma unroll
            for (int nio = 0; nio < 2; ++nio)
                oacc[mio][nio] = __builtin_amdgcn_mfma_f32_16x16x32_bf16(aw.v8, bvh[nio], oacc[mio][nio], 0, 0, 0);
            __builtin_amdgcn_s_setprio(0);
        }
    }
    float invO[2][4];
#pragma unroll
    for (int mio = 0; mio < 2; ++mio)
#pragma unroll
        for (int r = 0; r < 4; ++r)
            invO[mio][r] = __shfl(mio ? i1 : i0, sct * 4 + r);
#pragma unroll
    for (int mio = 0; mio < 2; ++mio)
#pragma unroll
        for (int nio = 0; nio < 2; ++nio)
#pragma unroll
            for (int r = 0; r < 4; ++r) {
                int token = w * 32 + mio * 16 + sct * 4 + r;
                int d = (nio << 4) + l15;
                size_t idx = ((size_t)b * SEQN + token) * CDIM + h * HD + d;
                OH[idx] = bf16_rn(oacc[mio][nio][r] * invO[mio][r]);
            }
}

// ---------------------------------------------------------------------------
// K3: MFMA proj GEMM (A = single-bf16 O, B split -> 2-term) + bias + residual
// + LayerNorm, 32 tokens per block.  grid (480, 4), block 256.
__global__ __launch_bounds__(256, 4) void projln_kernel(
    const unsigned short* __restrict__ OHp,
    unsigned short* __restrict__ XH, unsigned short* __restrict__ XL,
    const unsigned short* __restrict__ W2H, const unsigned short* __restrict__ W2L,
    const float* __restrict__ PB, const float* __restrict__ G,
    const float* __restrict__ BB) {
    const int b = blockIdx.x;
    const int t0 = blockIdx.y * 32;
    __shared__ float vals[32 * 289];
    __shared__ float part[8][32][2];

    const int tid = threadIdx.x;
    const int w = tid >> 6;
    const int l = tid & 63;
    const int l15 = l & 15;
    const int sct = l >> 4;

    f32x4 acc[2][4];
#pragma unroll
    for (int mi = 0; mi < 2; ++mi)
#pragma unroll
        for (int ni = 0; ni < 4; ++ni) acc[mi][ni] = (f32x4){0.f, 0.f, 0.f, 0.f};

    const size_t obase = ((size_t)b * SEQN + t0) * CDIM;
#pragma unroll 2
    for (int ks = 0; ks < 8; ++ks) {
        const int kb = ks * 32;
        bf16x8 ahi[2];
#pragma unroll
        for (int mi = 0; mi < 2; ++mi) {
            size_t off = obase + (size_t)(mi * 16 + l15) * CDIM + kb + sct * 8;
            ahi[mi] = *reinterpret_cast<const bf16x8*>(OHp + off);
        }
#pragma unroll
        for (int ni = 0; ni < 4; ++ni) {
            int j = w * 64 + ni * 16 + l15;
            int woff = j * 256 + kb + sct * 8;
            bf16x8 bh = *reinterpret_cast<const bf16x8*>(W2H + woff);
            bf16x8 bl = *reinterpret_cast<const bf16x8*>(W2L + woff);
#pragma unroll
            for (int mi = 0; mi < 2; ++mi) {
                acc[mi][ni] = __builtin_amdgcn_mfma_f32_16x16x32_bf16(ahi[mi], bh, acc[mi][ni], 0, 0, 0);
                acc[mi][ni] = __builtin_amdgcn_mfma_f32_16x16x32_bf16(ahi[mi], bl, acc[mi][ni], 0, 0, 0);
            }
        }
    }
#pragma unroll
    for (int ni = 0; ni < 4; ++ni) {
        int j = w * 64 + ni * 16 + l15;
        float bias = PB[j];
#pragma unroll
        for (int mi = 0; mi < 2; ++mi)
#pragma unroll
            for (int r = 0; r < 4; ++r) {
                int tok = mi * 16 + sct * 4 + r;
                vals[tok * 289 + j] = acc[mi][ni][r] + bias;
            }
    }
    __syncthreads();

    const int row = tid & 31;
    const int cc = tid >> 5;
    const size_t rbase = ((size_t)b * SEQN + t0 + row) * CDIM + cc * 32;
    float v[32];
    {
        float ps = 0.f, pq = 0.f;
#pragma unroll
        for (int q = 0; q < 4; ++q) {
            uint4 hb = *reinterpret_cast<const uint4*>(XH + rbase + q * 8);
            uint4 lb = *reinterpret_cast<const uint4*>(XL + rbase + q * 8);
            float rh[8], rl[8];
            unpack_bf16x8(hb, rh);
            unpack_bf16x8(lb, rl);
#pragma unroll
            for (int jj = 0; jj < 8; ++jj) {
                int col = cc * 32 + q * 8 + jj;
                float val = vals[row * 289 + col] + rh[jj] + rl[jj];
                v[q * 8 + jj] = val;
                ps += val;
                pq = fmaf(val, val, pq);
            }
        }
        part[cc][row][0] = ps;
        part[cc][row][1] = pq;
    }
    __syncthreads();
    float s1 = 0.f, s2 = 0.f;
#pragma unroll
    for (int k = 0; k < 8; ++k) { s1 += part[k][row][0]; s2 += part[k][row][1]; }
    float m = s1 * (1.f / 256.f);
    float var = s2 * (1.f / 256.f) - m * m;
    float rstd = rsqrtf(var + 1e-5f);
#pragma unroll
    for (int q = 0; q < 4; ++q) {
        int col0 = cc * 32 + q * 8;
        float4 g0 = *reinterpret_cast<const float4*>(G + col0);
        float4 g1 = *reinterpret_cast<const float4*>(G + col0 + 4);
        float4 b0 = *reinterpret_cast<const float4*>(BB + col0);
        float4 b1 = *reinterpret_cast<const float4*>(BB + col0 + 4);
        float gg[8] = {g0.x, g0.y, g0.z, g0.w, g1.x, g1.y, g1.z, g1.w};
        float bb2[8] = {b0.x, b0.y, b0.z, b0.w, b1.x, b1.y, b1.z, b1.w};
        unsigned hw[4], lw[4];
#pragma unroll
        for (int p2 = 0; p2 < 4; ++p2) {
            float y0 = (v[q * 8 + p2 * 2] - m) * rstd * gg[p2 * 2] + bb2[p2 * 2];
            float y1 = (v[q * 8 + p2 * 2 + 1] - m) * rstd * gg[p2 * 2 + 1] + bb2[p2 * 2 + 1];
            unsigned short h0 = bf16_rn(y0), h1 = bf16_rn(y1);
            unsigned short lo0 = bf16_rn(y0 - bf16f(h0)), lo1 = bf16_rn(y1 - bf16f(h1));
            hw[p2] = (unsigned)h0 | ((unsigned)h1 << 16);
            lw[p2] = (unsigned)lo0 | ((unsigned)lo1 << 16);
        }
        *reinterpret_cast<uint4*>(XH + rbase + q * 8) = make_uint4(hw[0], hw[1], hw[2], hw[3]);
        *reinterpret_cast<uint4*>(XL + rbase + q * 8) = make_uint4(lw[0], lw[1], lw[2], lw[3]);
    }
}

// ---------------------------------------------------------------------------
// K4: mean over tokens + classifier head (reads planes). grid 480, block 256.
__global__ __launch_bounds__(256) void cls_kernel(const unsigned short* __restrict__ XH,
                                                  const unsigned short* __restrict__ XL,
                                                  const float* __restrict__ W1,
                                                  const float* __restrict__ B1,
                                                  const float* __restrict__ W2,
                                                  const float* __restrict__ B2,
                                                  float* __restrict__ OUT) {
    int b = blockIdx.x;
    __shared__ float xm[256];
    __shared__ float hred[128];
    int tid = threadIdx.x;
    float sm = 0.f;
    for (int n = 0; n < SEQN; ++n) {
        size_t idx = ((size_t)b * SEQN + n) * CDIM + tid;
        sm += bf16f(XH[idx]) + bf16f(XL[idx]);
    }
    xm[tid] = sm * (1.f / 128.f);
    __syncthreads();
    if (tid < 128) {
        float a = B1[tid];
        for (int k = 0; k < CDIM; ++k) a = fmaf(xm[k], W1[k * 128 + tid], a);
        a = fmaxf(a, 0.f);
        hred[tid] = a * W2[tid];
    }
    __syncthreads();
    for (int off = 64; off > 0; off >>= 1) {
        if (tid < off) hred[tid] += hred[tid + off];
        __syncthreads();
    }
    if (tid == 0) OUT[b] = hred[0] + B2[0];
}

// ---------------------------------------------------------------------------
extern "C" void kernel_launch(void* const* d_in, const int* in_sizes, int n_in,
                              void* d_out, int out_size, void* d_ws, size_t ws_size,
                              hipStream_t stream) {
    const float* RW  = (const float*)d_in[0];
    const float* POS = (const float*)d_in[1];
    const float* CW1 = (const float*)d_in[2];
    const float* CB1 = (const float*)d_in[3];
    const float* CW2 = (const float*)d_in[4];
    const float* CB2 = (const float*)d_in[5];

    const size_t NTOK = (size_t)NSEQ * SEQN * CDIM;  // 15.7M
    const size_t QN = (size_t)768 * 256, PN = (size_t)256 * 256;
    const size_t LSTRIDE = 2 * QN + 2 * PN;
    unsigned short* OH = (unsigned short*)d_ws;       // 31.5 MB
    unsigned short* XH = OH + NTOK;                   // 31.5 MB
    unsigned short* XL = XH + NTOK;                   // 31.5 MB
    unsigned short* WBUF = XL + NTOK;                 // 2 layers x 1.05 MB

    prep_kernel<<<dim3(NSEQ, 4, 8), 256, 0, stream>>>(RW, POS, XH, XL);
    wsplit_all_kernel<<<dim3(8, 64), 256, 0, stream>>>(
        (const float*)d_in[6], (const float*)d_in[8],
        (const float*)d_in[12], (const float*)d_in[14], WBUF);

    for (int li = 0; li < 2; ++li) {
        const float* qb = (const float*)d_in[7 + 6 * li];
        const float* pb = (const float*)d_in[9 + 6 * li];
        const float* lg = (const float*)d_in[10 + 6 * li];
        const float* lb = (const float*)d_in[11 + 6 * li];
        unsigned short* WtHi = WBUF + li * LSTRIDE;
        unsigned short* WtLo = WtHi + QN;
        unsigned short* W2H = WtHi + 2 * QN;
        unsigned short* W2L = W2H + PN;
        attn_kernel<<<NSEQ * NH, 256, 0, stream>>>(XH, XL, OH, WtHi, WtLo, qb);
        projln_kernel<<<dim3(NSEQ, 4), 256, 0, stream>>>(OH, XH, XL, W2H, W2L, pb, lg, lb);
    }

    cls_kernel<<<NSEQ, 256, 0, stream>>>(XH, XL, CW1, CB1, CW2, CB2, (float*)d_out);
}